// Round 8
// baseline (47.850 us; speedup 1.0000x reference)
//
#include <hip/hip_runtime.h>
#include <math.h>

#define TB 256
#define S_LEN 8000
#define B_N 128
#define BPB 11           // sibling blocks per batch
#define TPB 3            // 256-row tiles per block; 11*3=33 tile slots >= 32 (tail guarded)
#define GRID (B_N * BPB) // 1408 blocks; capacity 7/CU = 1792 slots (27% margin)
#define CTRW 32          // uints per counter slot (128 B padding)

// ---------------- bf16 helpers (RNE) ----------------
__device__ __forceinline__ unsigned short bf16_rne(float f) {
  unsigned u = __float_as_uint(f);
  return (unsigned short)((u + 0x7FFFu + ((u >> 16) & 1u)) >> 16);
}
__device__ __forceinline__ float bf16_f(unsigned short h) {
  return __uint_as_float(((unsigned)h) << 16);
}
__device__ __forceinline__ void load_row(const unsigned short* __restrict__ r, float* y) {
#pragma unroll
  for (int j = 0; j < 9; ++j) y[j] = bf16_f(r[j]);
}

// ---------------- math helpers ----------------

// erf via Taylor for |z|<0.5 (err < 1e-5); here |z| << 0.5 (softmax weights
// ~1/8000 => |t| < 0.1); erff fallback never taken in practice.
__device__ __forceinline__ float erf_fast(float z) {
  float z2 = z * z;
  if (__builtin_expect(z2 > 0.25f, 0)) return erff(z);
  const float c0 = 1.1283791670955126f;  // 2/sqrt(pi)
  return c0 * z * (1.f + z2 * (-1.f / 3.f + z2 * (0.1f - z2 * (1.f / 42.f))));
}

// W/bias straight from global: uniform pointer + constant indices -> scalar
// (SGPR) loads, v_fma with SGPR operand; zero LDS/VALU staging overhead.
__device__ __forceinline__ void matvec89(const float* __restrict__ W, const float* __restrict__ bias,
                                         const float* __restrict__ y, float* out) {
#pragma unroll
  for (int i = 0; i < 8; ++i) {
    float a = bias[i];
#pragma unroll
    for (int j = 0; j < 9; ++j) a += W[i * 9 + j] * y[j];
    out[i] = a;
  }
}

__device__ __forceinline__ float head_scale(const float* q, const float* v, const float* bindS,
                                            int h, float maskv) {
  float q0 = q[2 * h], q1 = q[2 * h + 1];
  float v0 = v[2 * h], v1 = v[2 * h + 1];
  float B0 = bindS[2 * h], B1 = bindS[2 * h + 1];
  // HD=2: real 2-pt FFT self-conjugate -> unbinding == circular conv
  float vp0 = B0 * q0 + B1 * q1;
  float vp1 = B0 * q1 + B1 * q0;
  float num = v0 * vp0 + v1 * vp1;
  // max(sqrt(a2),1e-8) == sqrt(max(a2,1e-16)) -> rsqrt form, no sqrt/div
  float a2 = fmaxf(v0 * v0 + v1 * v1, 1e-16f);
  float b2 = fmaxf(vp0 * vp0 + vp1 * vp1, 1e-16f);
  float sc = num * rsqrtf(a2) * rsqrtf(b2);
  sc += (1.f - maskv) * (-1e9f);
  return sc;
}

// Per-batch barrier among BPB siblings: fully RELAXED agent atomics (served at
// the coherence point, no cache maintenance). Ordering: __syncthreads drains
// vmcnt, so sibling data stores hit the LLC before the arrival add. (validated r6/r7)
__device__ __forceinline__ void batch_barrier(unsigned* ctr, int tid) {
  __syncthreads();
  if (tid == 0) {
    __hip_atomic_fetch_add(ctr, 1u, __ATOMIC_RELAXED, __HIP_MEMORY_SCOPE_AGENT);
    while (__hip_atomic_load(ctr, __ATOMIC_RELAXED, __HIP_MEMORY_SCOPE_AGENT) < (unsigned)BPB)
      __builtin_amdgcn_s_sleep(8);
  }
  __syncthreads();
}

// ---------------- fused kernel ----------------
__global__ __launch_bounds__(TB, 7) void k_fused(
    const float* __restrict__ x, const float* __restrict__ mask, const float* __restrict__ pos,
    const float* __restrict__ lng, const float* __restrict__ lnb,
    const float* __restrict__ Wq, const float* __restrict__ bq,
    const float* __restrict__ Wk, const float* __restrict__ bk,
    const float* __restrict__ Wv, const float* __restrict__ bv,
    const float* __restrict__ W2, const float* __restrict__ b2,
    const float* __restrict__ Wo, const float* __restrict__ bo,
    unsigned* __restrict__ ctr1, unsigned* __restrict__ ctr2,
    float* __restrict__ bindP, float* __restrict__ sumP,
    float* __restrict__ out) {
  __shared__ unsigned short ys[TPB][TB * 9];  // LN output in bf16 (13.8 KB)
  __shared__ float red[4 * 8];
  __shared__ float bindS[8], invDS[4];

  const int tid = threadIdx.x, bid = blockIdx.x;
  const int b = bid / BPB;             // batch 0..127
  const int t0 = (bid % BPB) * TPB;    // first tile (0,3,...,30)
  const int wave = tid >> 6, lane = tid & 63;
  const float* maskb = mask + (size_t)b * 4 * S_LEN;

  int nrowA[TPB];
#pragma unroll
  for (int t = 0; t < TPB; ++t) nrowA[t] = min(TB, S_LEN - (t0 + t) * TB);  // may be <= 0

  // ---- phase 0: stage x+pos once (float4 -> bf16x4), LayerNorm in place ----
#pragma unroll
  for (int t = 0; t < TPB; ++t) {
    if (nrowA[t] <= 0) continue;
    const int s0 = (t0 + t) * TB;
    const int n4 = (nrowA[t] * 9) >> 2;           // nrow in {256,64}: divisible by 4
    const float4* xb4 = (const float4*)(x + ((size_t)b * S_LEN + s0) * 9);
    const float4* pb4 = (const float4*)(pos + (size_t)s0 * 9);
    short4* yd = (short4*)ys[t];                  // 8-B aligned stores
    for (int i = tid; i < n4; i += TB) {
      float4 a = xb4[i], p = pb4[i];
      yd[i] = make_short4((short)bf16_rne(a.x + p.x), (short)bf16_rne(a.y + p.y),
                          (short)bf16_rne(a.z + p.z), (short)bf16_rne(a.w + p.w));
    }
  }
  __syncthreads();
#pragma unroll
  for (int t = 0; t < TPB; ++t) {
    if (tid < nrowA[t]) {
      unsigned short* r = &ys[t][tid * 9];
      float v[9], m = 0.f;
#pragma unroll
      for (int j = 0; j < 9; ++j) { v[j] = bf16_f(r[j]); m += v[j]; }
      m *= (1.f / 9.f);
      float var = 0.f;
#pragma unroll
      for (int j = 0; j < 9; ++j) { float d = v[j] - m; var += d * d; }
      var *= (1.f / 9.f);
      float rs = rsqrtf(var + 1e-6f);
#pragma unroll
      for (int j = 0; j < 9; ++j) r[j] = bf16_rne((v[j] - m) * rs * lng[j] + lnb[j]);
    }
  }
  // rows are thread-private after this point: no sync needed before reads

  // ---- phase 1: k,v matvecs; vv kept in regs; bind accumulation ----
  float vv[TPB][8];   // held across both barriers (24 VGPR, static indexing)
  float acc[8];
#pragma unroll
  for (int i = 0; i < 8; ++i) acc[i] = 0.f;
#pragma unroll
  for (int t = 0; t < TPB; ++t) {
    if (tid < nrowA[t]) {
      float y[9];
      load_row(&ys[t][tid * 9], y);
      float kk[8];
      matvec89(Wk, bk, y, kk);
      matvec89(Wv, bv, y, vv[t]);
#pragma unroll
      for (int h = 0; h < 4; ++h) {
        float k0 = kk[2 * h], k1 = kk[2 * h + 1];
        float v0 = vv[t][2 * h], v1 = vv[t][2 * h + 1];
        acc[2 * h]     += k0 * v0 + k1 * v1;
        acc[2 * h + 1] += k0 * v1 + k1 * v0;
      }
    }
  }
#pragma unroll
  for (int i = 0; i < 8; ++i) {
#pragma unroll
    for (int off = 32; off > 0; off >>= 1) acc[i] += __shfl_down(acc[i], off, 64);
  }
  __syncthreads();
  if (lane == 0) {
#pragma unroll
    for (int i = 0; i < 8; ++i) red[wave * 8 + i] = acc[i];
  }
  __syncthreads();
  if (tid < 8) {
    float s = red[tid] + red[8 + tid] + red[16 + tid] + red[24 + tid];
    __hip_atomic_store(&bindP[bid * 8 + tid], s, __ATOMIC_RELAXED, __HIP_MEMORY_SCOPE_AGENT);
  }

  batch_barrier(&ctr1[b * CTRW], tid);

  if (tid < 8) {
    float s = 0.f;
#pragma unroll
    for (int j = 0; j < BPB; ++j)
      s += __hip_atomic_load(&bindP[(b * BPB + j) * 8 + tid],
                             __ATOMIC_RELAXED, __HIP_MEMORY_SCOPE_AGENT);
    bindS[tid] = s;
  }
  __syncthreads();

  // ---- phase 2: q matvec + e numerators (regs) + denominator partials ----
  float e[TPB][4];
  float esum[4] = {0.f, 0.f, 0.f, 0.f};
#pragma unroll
  for (int t = 0; t < TPB; ++t) {
    const int s0 = (t0 + t) * TB;
#pragma unroll
    for (int h = 0; h < 4; ++h) e[t][h] = 0.f;
    if (tid < nrowA[t]) {
      float y[9];
      load_row(&ys[t][tid * 9], y);
      float qq[8];
      matvec89(Wq, bq, y, qq);
#pragma unroll
      for (int h = 0; h < 4; ++h) {
        float m = maskb[(size_t)h * S_LEN + s0 + tid];
        e[t][h] = __expf(head_scale(qq, vv[t], bindS, h, m));  // |cos|<=1: no max-sub
        esum[h] += e[t][h];
      }
    }
  }
#pragma unroll
  for (int h = 0; h < 4; ++h) {
#pragma unroll
    for (int off = 32; off > 0; off >>= 1) esum[h] += __shfl_down(esum[h], off, 64);
  }
  __syncthreads();
  if (lane == 0) {
#pragma unroll
    for (int h = 0; h < 4; ++h) red[wave * 4 + h] = esum[h];
  }
  __syncthreads();
  if (tid < 4) {
    float s = red[tid] + red[4 + tid] + red[8 + tid] + red[12 + tid];
    __hip_atomic_store(&sumP[bid * 4 + tid], s, __ATOMIC_RELAXED, __HIP_MEMORY_SCOPE_AGENT);
  }

  batch_barrier(&ctr2[b * CTRW], tid);

  if (tid < 4) {
    float s = 0.f;
#pragma unroll
    for (int j = 0; j < BPB; ++j)
      s += __hip_atomic_load(&sumP[(b * BPB + j) * 4 + tid],
                             __ATOMIC_RELAXED, __HIP_MEMORY_SCOPE_AGENT);
    invDS[tid] = 1.f / s;
  }
  __syncthreads();

  // ---- phase 3: attn from regs, FFN (poly-erf gelu), output ----
#pragma unroll
  for (int t = 0; t < TPB; ++t) {
    const int s0 = (t0 + t) * TB;
    if (tid < nrowA[t]) {
      float y[9];
      load_row(&ys[t][tid * 9], y);
      float w0 = e[t][0] * invDS[0], w1 = e[t][1] * invDS[1];
      float w2 = e[t][2] * invDS[2], w3 = e[t][3] * invDS[3];
      float attn[8] = {w0 * vv[t][0], w0 * vv[t][1], w1 * vv[t][2], w1 * vv[t][3],
                       w2 * vv[t][4], w2 * vv[t][5], w3 * vv[t][6], w3 * vv[t][7]};
      float o = bo[0];
#pragma unroll
      for (int i = 0; i < 9; ++i) {
        float tt = b2[i];
#pragma unroll
        for (int j = 0; j < 8; ++j) tt += W2[i * 8 + j] * attn[j];
        float g = 0.5f * tt * (1.f + erf_fast(tt * 0.70710678118654752f));
        o += Wo[i] * (g + y[i]);
      }
      out[(size_t)b * S_LEN + s0 + tid] = o;
    }
  }
}

// ---------------- launch ----------------

extern "C" void kernel_launch(void* const* d_in, const int* in_sizes, int n_in,
                              void* d_out, int out_size, void* d_ws, size_t ws_size,
                              hipStream_t stream) {
  const float* x    = (const float*)d_in[0];
  const float* mask = (const float*)d_in[1];
  const float* pos  = (const float*)d_in[2];
  const float* lng  = (const float*)d_in[3];
  const float* lnb  = (const float*)d_in[4];
  const float* Wq   = (const float*)d_in[5];
  const float* bq   = (const float*)d_in[6];
  const float* Wk   = (const float*)d_in[7];
  const float* bk   = (const float*)d_in[8];
  const float* Wv   = (const float*)d_in[9];
  const float* bv   = (const float*)d_in[10];
  // d_in[11] = W1, d_in[12] = b1 (dead in reference)
  const float* W2   = (const float*)d_in[13];
  const float* b2   = (const float*)d_in[14];
  const float* Wo   = (const float*)d_in[15];
  const float* bo   = (const float*)d_in[16];
  float* out = (float*)d_out;

  // ws: [ctr1 128*32 u32][ctr2 128*32 u32][bindP 1408*8 f32][sumP 1408*4 f32]
  unsigned* ctr1  = (unsigned*)d_ws;
  unsigned* ctr2  = ctr1 + B_N * CTRW;
  float*    bindP = (float*)(ctr2 + B_N * CTRW);
  float*    sumP  = bindP + GRID * 8;

  hipMemsetAsync(d_ws, 0, 2 * B_N * CTRW * sizeof(unsigned), stream);
  k_fused<<<GRID, TB, 0, stream>>>(x, mask, pos, lng, lnb, Wq, bq, Wk, bk, Wv, bv,
                                   W2, b2, Wo, bo, ctr1, ctr2, bindP, sumP, out);
}

// Round 9
// 39.316 us; speedup vs baseline: 1.2170x; 1.2170x over previous
//
#include <hip/hip_runtime.h>
#include <math.h>

#define TB 256
#define S_LEN 8000
#define B_N 128
#define BPB 8            // sibling blocks per batch (share the two reductions)
#define TPB 4            // 256-row tiles per block: 8*4*256 >= 8000
#define GRID (B_N * BPB) // 1024 blocks; co-resident at 4 blocks/CU (launch_bounds)
#define CTRW 32          // uints per counter slot (128 B padding)

// ---------------- math helpers ----------------

// erf via Taylor for |z|<0.5 (err < 1e-5); here |z| << 0.5 (softmax weights
// ~1/8000 => |t| < 0.1); erff fallback never taken in practice.
__device__ __forceinline__ float erf_fast(float z) {
  float z2 = z * z;
  if (__builtin_expect(z2 > 0.25f, 0)) return erff(z);
  const float c0 = 1.1283791670955126f;  // 2/sqrt(pi)
  return c0 * z * (1.f + z2 * (-1.f / 3.f + z2 * (0.1f - z2 * (1.f / 42.f))));
}

// W/bias straight from global: uniform pointer + constant indices -> scalar
// (SGPR) loads, v_fma with SGPR operand; zero LDS/VALU staging overhead.
__device__ __forceinline__ void matvec89(const float* __restrict__ W, const float* __restrict__ bias,
                                         const float* __restrict__ y, float* out) {
#pragma unroll
  for (int i = 0; i < 8; ++i) {
    float a = bias[i];
#pragma unroll
    for (int j = 0; j < 9; ++j) a += W[i * 9 + j] * y[j];
    out[i] = a;
  }
}

__device__ __forceinline__ float head_scale(const float* q, const float* v, const float* bindS,
                                            int h, float maskv) {
  float q0 = q[2 * h], q1 = q[2 * h + 1];
  float v0 = v[2 * h], v1 = v[2 * h + 1];
  float B0 = bindS[2 * h], B1 = bindS[2 * h + 1];
  // HD=2: real 2-pt FFT self-conjugate -> unbinding == circular conv
  float vp0 = B0 * q0 + B1 * q1;
  float vp1 = B0 * q1 + B1 * q0;
  float num = v0 * vp0 + v1 * vp1;
  // max(sqrt(a2),1e-8) == sqrt(max(a2,1e-16)) -> rsqrt form, no sqrt/div
  float a2 = fmaxf(v0 * v0 + v1 * v1, 1e-16f);
  float b2 = fmaxf(vp0 * vp0 + vp1 * vp1, 1e-16f);
  float sc = num * rsqrtf(a2) * rsqrtf(b2);
  sc += (1.f - maskv) * (-1e9f);
  return sc;
}

// Per-batch barrier among BPB siblings: fully RELAXED agent atomics (served at
// the coherence point, no cache maintenance). Ordering: __syncthreads drains
// vmcnt, so sibling data stores hit the LLC before the arrival add. (validated r6/r7)
__device__ __forceinline__ void batch_barrier(unsigned* ctr, int tid) {
  __syncthreads();
  if (tid == 0) {
    __hip_atomic_fetch_add(ctr, 1u, __ATOMIC_RELAXED, __HIP_MEMORY_SCOPE_AGENT);
    while (__hip_atomic_load(ctr, __ATOMIC_RELAXED, __HIP_MEMORY_SCOPE_AGENT) < (unsigned)BPB)
      __builtin_amdgcn_s_sleep(8);
  }
  __syncthreads();
}

// ---------------- fused kernel (all row state in registers) ----------------
__global__ __launch_bounds__(TB, 4) void k_fused(
    const float* __restrict__ x, const float* __restrict__ mask, const float* __restrict__ pos,
    const float* __restrict__ lng, const float* __restrict__ lnb,
    const float* __restrict__ Wq, const float* __restrict__ bq,
    const float* __restrict__ Wk, const float* __restrict__ bk,
    const float* __restrict__ Wv, const float* __restrict__ bv,
    const float* __restrict__ W2, const float* __restrict__ b2,
    const float* __restrict__ Wo, const float* __restrict__ bo,
    unsigned* __restrict__ ctr1, unsigned* __restrict__ ctr2,
    float* __restrict__ bindP, float* __restrict__ sumP,
    float* __restrict__ out) {
  __shared__ float red[4 * 8];
  __shared__ float sib[BPB * 8];        // parallel post-barrier sibling loads
  __shared__ float bindS[8], invDS[4];

  const int tid = threadIdx.x, bid = blockIdx.x;
  const int b = bid >> 3;               // batch 0..127
  const int t0 = (bid & 7) * TPB;       // first tile (0,4,...,28)
  const int wave = tid >> 6, lane = tid & 63;
  const float* maskb = mask + (size_t)b * 4 * S_LEN;

  int nrowA[TPB];
#pragma unroll
  for (int t = 0; t < TPB; ++t) nrowA[t] = min(TB, S_LEN - (t0 + t) * TB);

  // ---- phase 0+1: load row, LN (regs), k/v matvecs, bind accumulation ----
  float y[TPB][9];    // LN output, register-resident across all phases
  float vv[TPB][8];   // v-projection, register-resident
  float acc[8];
#pragma unroll
  for (int i = 0; i < 8; ++i) acc[i] = 0.f;

#pragma unroll
  for (int t = 0; t < TPB; ++t) {
    if (tid < nrowA[t]) {
      const int s = (t0 + t) * TB + tid;
      const float* xr = x + ((size_t)b * S_LEN + s) * 9;
      const float* pr = pos + (size_t)s * 9;
      float m = 0.f;
#pragma unroll
      for (int j = 0; j < 9; ++j) { y[t][j] = xr[j] + pr[j]; m += y[t][j]; }
      m *= (1.f / 9.f);
      float var = 0.f;
#pragma unroll
      for (int j = 0; j < 9; ++j) { float d = y[t][j] - m; var += d * d; }
      var *= (1.f / 9.f);
      float rs = rsqrtf(var + 1e-6f);
#pragma unroll
      for (int j = 0; j < 9; ++j) y[t][j] = (y[t][j] - m) * rs * lng[j] + lnb[j];

      float kk[8];
      matvec89(Wk, bk, y[t], kk);
      matvec89(Wv, bv, y[t], vv[t]);
#pragma unroll
      for (int h = 0; h < 4; ++h) {
        float k0 = kk[2 * h], k1 = kk[2 * h + 1];
        float v0 = vv[t][2 * h], v1 = vv[t][2 * h + 1];
        acc[2 * h]     += k0 * v0 + k1 * v1;
        acc[2 * h + 1] += k0 * v1 + k1 * v0;
      }
    }
  }
#pragma unroll
  for (int i = 0; i < 8; ++i) {
#pragma unroll
    for (int off = 32; off > 0; off >>= 1) acc[i] += __shfl_down(acc[i], off, 64);
  }
  __syncthreads();
  if (lane == 0) {
#pragma unroll
    for (int i = 0; i < 8; ++i) red[wave * 8 + i] = acc[i];
  }
  __syncthreads();
  if (tid < 8) {
    float s = red[tid] + red[8 + tid] + red[16 + tid] + red[24 + tid];
    __hip_atomic_store(&bindP[bid * 8 + tid], s, __ATOMIC_RELAXED, __HIP_MEMORY_SCOPE_AGENT);
  }

  batch_barrier(&ctr1[b * CTRW], tid);

  // 64 parallel agent loads (one per lane) instead of 8 serial per thread
  if (tid < BPB * 8)
    sib[tid] = __hip_atomic_load(&bindP[(b * BPB + (tid >> 3)) * 8 + (tid & 7)],
                                 __ATOMIC_RELAXED, __HIP_MEMORY_SCOPE_AGENT);
  __syncthreads();
  if (tid < 8) {
    float s = 0.f;
#pragma unroll
    for (int j = 0; j < BPB; ++j) s += sib[j * 8 + tid];
    bindS[tid] = s;
  }
  __syncthreads();

  // ---- phase 2: q matvec + e numerators (regs) + denominator partials ----
  float e[TPB][4];
  float esum[4] = {0.f, 0.f, 0.f, 0.f};
#pragma unroll
  for (int t = 0; t < TPB; ++t) {
    const int s0 = (t0 + t) * TB;
#pragma unroll
    for (int h = 0; h < 4; ++h) e[t][h] = 0.f;
    if (tid < nrowA[t]) {
      float qq[8];
      matvec89(Wq, bq, y[t], qq);
#pragma unroll
      for (int h = 0; h < 4; ++h) {
        float m = maskb[(size_t)h * S_LEN + s0 + tid];
        e[t][h] = __expf(head_scale(qq, vv[t], bindS, h, m));  // |cos|<=1: no max-sub
        esum[h] += e[t][h];
      }
    }
  }
#pragma unroll
  for (int h = 0; h < 4; ++h) {
#pragma unroll
    for (int off = 32; off > 0; off >>= 1) esum[h] += __shfl_down(esum[h], off, 64);
  }
  __syncthreads();
  if (lane == 0) {
#pragma unroll
    for (int h = 0; h < 4; ++h) red[wave * 4 + h] = esum[h];
  }
  __syncthreads();
  if (tid < 4) {
    float s = red[tid] + red[4 + tid] + red[8 + tid] + red[12 + tid];
    __hip_atomic_store(&sumP[bid * 4 + tid], s, __ATOMIC_RELAXED, __HIP_MEMORY_SCOPE_AGENT);
  }

  batch_barrier(&ctr2[b * CTRW], tid);

  if (tid < BPB * 4)
    sib[tid] = __hip_atomic_load(&sumP[(b * BPB + (tid >> 2)) * 4 + (tid & 3)],
                                 __ATOMIC_RELAXED, __HIP_MEMORY_SCOPE_AGENT);
  __syncthreads();
  if (tid < 4) {
    float s = 0.f;
#pragma unroll
    for (int j = 0; j < BPB; ++j) s += sib[j * 4 + tid];
    invDS[tid] = 1.f / s;
  }
  __syncthreads();

  // ---- phase 3: attn from regs, FFN (poly-erf gelu), output ----
#pragma unroll
  for (int t = 0; t < TPB; ++t) {
    const int s0 = (t0 + t) * TB;
    if (tid < nrowA[t]) {
      float w0 = e[t][0] * invDS[0], w1 = e[t][1] * invDS[1];
      float w2 = e[t][2] * invDS[2], w3 = e[t][3] * invDS[3];
      float attn[8] = {w0 * vv[t][0], w0 * vv[t][1], w1 * vv[t][2], w1 * vv[t][3],
                       w2 * vv[t][4], w2 * vv[t][5], w3 * vv[t][6], w3 * vv[t][7]};
      float o = bo[0];
#pragma unroll
      for (int i = 0; i < 9; ++i) {
        float tt = b2[i];
#pragma unroll
        for (int j = 0; j < 8; ++j) tt += W2[i * 8 + j] * attn[j];
        float g = 0.5f * tt * (1.f + erf_fast(tt * 0.70710678118654752f));
        o += Wo[i] * (g + y[t][i]);
      }
      out[(size_t)b * S_LEN + s0 + tid] = o;
    }
  }
}

// ---------------- launch ----------------

extern "C" void kernel_launch(void* const* d_in, const int* in_sizes, int n_in,
                              void* d_out, int out_size, void* d_ws, size_t ws_size,
                              hipStream_t stream) {
  const float* x    = (const float*)d_in[0];
  const float* mask = (const float*)d_in[1];
  const float* pos  = (const float*)d_in[2];
  const float* lng  = (const float*)d_in[3];
  const float* lnb  = (const float*)d_in[4];
  const float* Wq   = (const float*)d_in[5];
  const float* bq   = (const float*)d_in[6];
  const float* Wk   = (const float*)d_in[7];
  const float* bk   = (const float*)d_in[8];
  const float* Wv   = (const float*)d_in[9];
  const float* bv   = (const float*)d_in[10];
  // d_in[11] = W1, d_in[12] = b1 (dead in reference)
  const float* W2   = (const float*)d_in[13];
  const float* b2   = (const float*)d_in[14];
  const float* Wo   = (const float*)d_in[15];
  const float* bo   = (const float*)d_in[16];
  float* out = (float*)d_out;

  // ws: [ctr1 128*32 u32][ctr2 128*32 u32][bindP 1024*8 f32][sumP 1024*4 f32]
  unsigned* ctr1  = (unsigned*)d_ws;
  unsigned* ctr2  = ctr1 + B_N * CTRW;
  float*    bindP = (float*)(ctr2 + B_N * CTRW);
  float*    sumP  = bindP + GRID * 8;

  hipMemsetAsync(d_ws, 0, 2 * B_N * CTRW * sizeof(unsigned), stream);
  k_fused<<<GRID, TB, 0, stream>>>(x, mask, pos, lng, lnb, Wq, bq, Wk, bk, Wv, bv,
                                   W2, b2, Wo, bo, ctr1, ctr2, bindP, sumP, out);
}